// Round 4
// baseline (31.272 us; speedup 1.0000x reference)
//
#include <hip/hip_runtime.h>

#define FD 768
#define HD 256
#define NF 512
#define NC 512
#define PAIRS (NF * (NF - 1) / 2)   // 130816
#define NS 16                       // split-k factor
#define KSLICE (FD / NS)            // 48 — one staging round per block

// ---------------------------------------------------------------------------
// Kernel 1: split-K GEMM, 64x64 tile, 4x4 microtile, ONE staging round.
//   part[z][r][c] = sum_{d in slice z} E[r][d] * Wcat[d][c]
// Grid (8,8,16) = 1024 blocks -> 4 blocks/CU, 4 waves/SIMD.
// LDS: Es[64][52] f32 (A-reads: 4 bcast addrs/wave, pitch 13-quads -> 2 groups)
//      Ws[48][64] f32 (W-reads: 16 addrs spread 2/quad-group)
// ---------------------------------------------------------------------------
__global__ __launch_bounds__(256) void gemm_split_kernel(
    const float* __restrict__ E, const float* __restrict__ W1,
    float* __restrict__ part)
{
    __shared__ float Es[64 * 52];
    __shared__ float Ws[48 * 64];

    const int tid = threadIdx.x;
    const int bx = blockIdx.x, by = blockIdx.y, bz = blockIdx.z;
    const int r0    = by * 64;
    const int c0g   = bx * 64;
    const int c0w   = c0g & 255;
    const int dofs  = (c0g >= 256) ? FD : 0;
    const int dbase = bz * KSLICE;
    const int tx = tid & 15, ty = tid >> 4;

    // --- stage E-tile: 64 rows x 12 f4 (masked 16-lane rows, coalesced) ---
    #pragma unroll
    for (int s = 0; s < 4; ++s) {
        int e = tid + 256 * s;
        int er = e >> 4, ec = e & 15;
        if (ec < 12) {
            float4 v = *(const float4*)&E[(r0 + er) * FD + dbase + 4 * ec];
            *(float4*)&Es[er * 52 + 4 * ec] = v;
        }
    }
    // --- stage W-tile: 48 rows x 16 f4, fully coalesced ---
    #pragma unroll
    for (int s = 0; s < 3; ++s) {
        int e = tid + 256 * s;
        int wr = e >> 4, wc = e & 15;
        float4 w = *(const float4*)&W1[(dofs + dbase + wr) * HD + c0w + 4 * wc];
        *(float4*)&Ws[wr * 64 + 4 * wc] = w;
    }
    __syncthreads();

    float4 acc0 = {0,0,0,0}, acc1 = {0,0,0,0}, acc2 = {0,0,0,0}, acc3 = {0,0,0,0};

    #pragma unroll
    for (int kq = 0; kq < KSLICE / 4; ++kq) {
        float4 a0 = *(const float4*)&Es[(4 * ty + 0) * 52 + 4 * kq];
        float4 a1 = *(const float4*)&Es[(4 * ty + 1) * 52 + 4 * kq];
        float4 a2 = *(const float4*)&Es[(4 * ty + 2) * 52 + 4 * kq];
        float4 a3 = *(const float4*)&Es[(4 * ty + 3) * 52 + 4 * kq];
        float4 w0 = *(const float4*)&Ws[(4 * kq + 0) * 64 + 4 * tx];
        float4 w1 = *(const float4*)&Ws[(4 * kq + 1) * 64 + 4 * tx];
        float4 w2 = *(const float4*)&Ws[(4 * kq + 2) * 64 + 4 * tx];
        float4 w3 = *(const float4*)&Ws[(4 * kq + 3) * 64 + 4 * tx];
        #define FMA4(ACC, S, W) \
            ACC.x = fmaf(S, W.x, ACC.x); ACC.y = fmaf(S, W.y, ACC.y); \
            ACC.z = fmaf(S, W.z, ACC.z); ACC.w = fmaf(S, W.w, ACC.w);
        FMA4(acc0, a0.x, w0) FMA4(acc0, a0.y, w1) FMA4(acc0, a0.z, w2) FMA4(acc0, a0.w, w3)
        FMA4(acc1, a1.x, w0) FMA4(acc1, a1.y, w1) FMA4(acc1, a1.z, w2) FMA4(acc1, a1.w, w3)
        FMA4(acc2, a2.x, w0) FMA4(acc2, a2.y, w1) FMA4(acc2, a2.z, w2) FMA4(acc2, a2.w, w3)
        FMA4(acc3, a3.x, w0) FMA4(acc3, a3.y, w1) FMA4(acc3, a3.z, w2) FMA4(acc3, a3.w, w3)
        #undef FMA4
    }

    float* dst = &part[(size_t)bz * NF * NC + (size_t)(r0 + 4 * ty) * NC + c0g + 4 * tx];
    *(float4*)&dst[0 * NC] = acc0;
    *(float4*)&dst[1 * NC] = acc1;
    *(float4*)&dst[2 * NC] = acc2;
    *(float4*)&dst[3 * NC] = acc3;
}

// ---------------------------------------------------------------------------
// Kernel 2: C = sum_z part[z] (+ b1 on left half). 256 blocks x 256 thr.
// ---------------------------------------------------------------------------
__global__ __launch_bounds__(256) void reduce_kernel(
    const float* __restrict__ part, const float* __restrict__ b1,
    float* __restrict__ C)
{
    const int idx = blockIdx.x * 256 + threadIdx.x;   // f4 index, 0..65535
    const float4* p4 = (const float4*)part;
    float4 s = p4[idx];
    #pragma unroll
    for (int z = 1; z < NS; ++z) {
        float4 v = p4[z * (NF * NC / 4) + idx];
        s.x += v.x; s.y += v.y; s.z += v.z; s.w += v.w;
    }
    const int c4 = idx & 127;
    if (c4 < 64) {
        float4 b = ((const float4*)b1)[c4];
        s.x += b.x; s.y += b.y; s.z += b.z; s.w += b.w;
    }
    ((float4*)C)[idx] = s;
}

// ---------------------------------------------------------------------------
// Kernel 3: pair scores. 16x16 tile per block, 528 blocks (2/CU),
// 1 pair/thread. LDS float4 pitch 65 (A: 4 bcast addrs; B: 16 addrs spread
// 2/quad-group).
// ---------------------------------------------------------------------------
__global__ __launch_bounds__(256) void pair_kernel(
    const float* __restrict__ C, const float* __restrict__ W2,
    const float* __restrict__ b2, float* __restrict__ out)
{
    __shared__ float4 As[16 * 65];
    __shared__ float4 Bs[16 * 65];
    __shared__ float4 w2s[HD / 4];

    int rem = blockIdx.x, bi = 0;
    while (rem >= 32 - bi) { rem -= 32 - bi; ++bi; }
    const int bj = bi + rem;
    const int i0 = bi * 16, j0 = bj * 16;

    const int tid = threadIdx.x;
    ((float*)w2s)[tid] = W2[tid];

    const float4* C4 = (const float4*)C;   // row pitch 128 f4
    #pragma unroll
    for (int s = 0; s < 4; ++s) {
        int e = tid + 256 * s;
        int row = e >> 6, c4 = e & 63;
        As[row * 65 + c4] = C4[(i0 + row) * 128 + c4];        // A half
        Bs[row * 65 + c4] = C4[(j0 + row) * 128 + 64 + c4];   // B half
    }
    __syncthreads();

    const int tx = tid & 15, ty = tid >> 4;
    float acc = 0.f;
    #pragma unroll 8
    for (int k4 = 0; k4 < HD / 4; ++k4) {
        float4 a = As[ty * 65 + k4];
        float4 b = Bs[tx * 65 + k4];
        float4 w = w2s[k4];
        acc = fmaf(fmaxf(a.x + b.x, 0.f), w.x, acc);
        acc = fmaf(fmaxf(a.y + b.y, 0.f), w.y, acc);
        acc = fmaf(fmaxf(a.z + b.z, 0.f), w.z, acc);
        acc = fmaf(fmaxf(a.w + b.w, 0.f), w.w, acc);
    }

    const int i = i0 + ty, j = j0 + tx;
    if (j > i) {
        const int p = i * (2 * NF - i - 1) / 2 + (j - i - 1);
        out[p]             = (float)i;
        out[PAIRS + p]     = (float)j;
        out[2 * PAIRS + p] = acc + b2[0];
    }
}

extern "C" void kernel_launch(void* const* d_in, const int* in_sizes, int n_in,
                              void* d_out, int out_size, void* d_ws, size_t ws_size,
                              hipStream_t stream) {
    const float* E  = (const float*)d_in[0];
    const float* W1 = (const float*)d_in[1];
    const float* b1 = (const float*)d_in[2];
    const float* W2 = (const float*)d_in[3];
    const float* b2 = (const float*)d_in[4];
    float* out  = (float*)d_out;
    float* part = (float*)d_ws;                            // NS MiB partials
    float* C    = (float*)d_ws + (size_t)NS * NF * NC;     // 1 MiB reduced C

    gemm_split_kernel<<<dim3(8, 8, NS), 256, 0, stream>>>(E, W1, part);
    reduce_kernel<<<NF * NC / 4 / 256, 256, 0, stream>>>(part, b1, C);
    pair_kernel<<<528, 256, 0, stream>>>(C, W2, b2, out);
}